// Round 9
// baseline (1455.505 us; speedup 1.0000x reference)
//
#include <hip/hip_runtime.h>

// Entropic Sinkhorn EMD, B=2, N=4096, D=3, EPS=0.1, 20 iters.
// Round-9: R8's single-kernel fusion, but with a PLAIN launch (cooperative
// launch is rejected under the harness's stream capture -> silent no-op in
// R8). Co-residency is guaranteed by capacity arithmetic instead:
// __launch_bounds__(512,4) => VGPR<=128 => 16 waves/CU => 2 blocks/CU x
// 256 CUs = 512 slots >= 512 blocks, so ALL workgroups are resident and the
// epoch grid-barrier (monotone, __device__ globals, agent-scope atomics +
// __threadfence for cross-XCD visibility) cannot deadlock.
// Inner loop: R7's verified SGPR-row-constant / 1-float4-per-j stream.

#define N    4096
#define NT   512
#define RPB  16     // rows per block
#define NBLK 512    // 256 blocks per batch x 2 batches
#define NW   (NT / 64)
#define KIT  (N / NT)

constexpr float EPS_F  = 0.1f;
constexpr float SHIFT  = 60.0f;
constexpr float LOG_A  = -8.317766166719343f;   // -log(4096)
constexpr float C10L   = 14.426950408889634f;   // 10*log2(e)
constexpr float C20L   = 28.853900817779268f;   // 20*log2(e)
constexpr float SHIFTL = 86.56170245333781f;    // SHIFT*log2(e)
constexpr float NLN2T  = -0.06931471805599453f; // -ln2/10
constexpr float LN2    = 0.6931471805599453f;

extern "C" __device__ float __ocml_native_exp2_f32(float);

__device__ __forceinline__ float fast_exp2(float x) {
#if __has_builtin(__builtin_amdgcn_exp2f)
    return __builtin_amdgcn_exp2f(x);
#else
    return __ocml_native_exp2_f32(x);
#endif
}

__device__ __forceinline__ float rfl(float x) {
    return __int_as_float(__builtin_amdgcn_readfirstlane(__float_as_int(x)));
}

// ---- grid barrier state (device globals: zero-init at load; epoch is
// monotone so repeated graph replays stay consistent; ws re-poison can't
// touch these) ----
struct alignas(128) PadU { unsigned int v; unsigned int pad[31]; };
__device__ PadU g_bucket[32];
__device__ PadU g_root;
__device__ PadU g_epoch;

__device__ __forceinline__ void grid_barrier(int blk) {
    __syncthreads();
    if (threadIdx.x == 0) {
        __threadfence();   // release: make this block's writes device-visible
        unsigned my = __hip_atomic_load(&g_epoch.v, __ATOMIC_RELAXED,
                                        __HIP_MEMORY_SCOPE_AGENT);
        int bucket = blk & 31;
        unsigned old = __hip_atomic_fetch_add(&g_bucket[bucket].v, 1u,
                                              __ATOMIC_ACQ_REL, __HIP_MEMORY_SCOPE_AGENT);
        if (old == (NBLK / 32) - 1) {
            __hip_atomic_store(&g_bucket[bucket].v, 0u, __ATOMIC_RELAXED,
                               __HIP_MEMORY_SCOPE_AGENT);
            unsigned r = __hip_atomic_fetch_add(&g_root.v, 1u,
                                                __ATOMIC_ACQ_REL, __HIP_MEMORY_SCOPE_AGENT);
            if (r == 31u) {
                __hip_atomic_store(&g_root.v, 0u, __ATOMIC_RELAXED,
                                   __HIP_MEMORY_SCOPE_AGENT);
                __hip_atomic_fetch_add(&g_epoch.v, 1u, __ATOMIC_RELEASE,
                                       __HIP_MEMORY_SCOPE_AGENT);
            }
        }
        while (__hip_atomic_load(&g_epoch.v, __ATOMIC_RELAXED,
                                 __HIP_MEMORY_SCOPE_AGENT) == my)
            __builtin_amdgcn_s_sleep(2);
        __threadfence();   // acquire: don't use stale cached data
    }
    __syncthreads();
}

// One half-sweep over this block's RPB rows. Row constants pinned in SGPRs;
// columns streamed one float4/j (w = current h2 of the column dual).
// Epilogue writes the new raw dual and refreshes packRow.w = new h2.
__device__ __forceinline__ void half_sweep(
    float4*       packRow, const float4* packCol,
    const float*  wBaseRow, float* dualRaw,
    int b, int rowBase, int tid)
{
    float4*      rp = packRow  + (size_t)b * N + rowBase;
    const float* wb = wBaseRow + (size_t)b * N + rowBase;

    float X[RPB], Y[RPB], Z[RPB], S[RPB];
    #pragma unroll
    for (int r = 0; r < RPB; ++r) {
        float4 q = rp[r];
        X[r] = rfl(q.x * C20L);
        Y[r] = rfl(q.y * C20L);
        Z[r] = rfl(q.z * C20L);
        S[r] = rfl(wb[r]);                 // -10L|p_i|^2
    }

    const float4* cp = packCol + (size_t)b * N;

    float acc[RPB];
    #pragma unroll
    for (int r = 0; r < RPB; ++r) acc[r] = 0.0f;

    #pragma unroll
    for (int k = 0; k < KIT; ++k) {
        float4 p = cp[tid + NT * k];       // {xj, yj, zj, h2j}
        #pragma unroll
        for (int r = 0; r < RPB; ++r) {
            float t = fmaf(Z[r], p.z, p.w);
            t = fmaf(Y[r], p.y, t);
            t = fmaf(X[r], p.x, t);
            acc[r] += fast_exp2(t + S[r]);
        }
    }

    #pragma unroll
    for (int r = 0; r < RPB; ++r) {
        float a = acc[r];
        a += __shfl_xor(a, 32);
        a += __shfl_xor(a, 16);
        a += __shfl_xor(a, 8);
        a += __shfl_xor(a, 4);
        a += __shfl_xor(a, 2);
        a += __shfl_xor(a, 1);
        acc[r] = a;
    }
    __shared__ float sred[RPB][NW];
    const int wave = tid >> 6, lane = tid & 63;
    if (lane == 0) {
        #pragma unroll
        for (int r = 0; r < RPB; ++r) sred[r][wave] = acc[r];
    }
    __syncthreads();
    if (tid < RPB) {
        float s = 0.f;
        #pragma unroll
        for (int w = 0; w < NW; ++w) s += sred[tid][w];
        float dual = EPS_F * (LOG_A + SHIFT - log2f(s) * LN2);
        dualRaw[(size_t)b * N + rowBase + tid] = dual;
        ((float*)(rp + tid))[3] = fmaf(dual, C10L, SHIFTL + wb[tid]);
    }
    // no trailing __syncthreads needed; grid_barrier() starts with one.
}

__global__ __launch_bounds__(NT, 4) void fused_kernel(
    const float* __restrict__ gen, const float* __restrict__ gt,
    float4* __restrict__ genPack, float4* __restrict__ gtPack,
    float* __restrict__ wBaseGen, float* __restrict__ wBaseGt,
    float* __restrict__ f, float* __restrict__ g,
    float* __restrict__ out)
{
    const int tid = threadIdx.x;
    const int blk = blockIdx.x;        // 0..511
    const int b   = blk >> 8;          // 0 or 1
    const int rowBase = (blk & 255) * RPB;

    // ---- prep: pack {x,y,z, h2(g=0)=SHIFTL-10L|p|^2}, wBase, zero f/g/out
    {
        int t = blk * NT + tid;        // first 32 blocks cover 16384 entries
        if (t < 16384) {
            int cloud = t >> 13;
            int idx   = t & 8191;      // b*N + j
            const float* src = cloud ? gt : gen;
            float x = src[idx * 3 + 0];
            float y = src[idx * 3 + 1];
            float z = src[idx * 3 + 2];
            float nb = -C10L * fmaf(z, z, fmaf(y, y, x * x));
            (cloud ? gtPack : genPack)[idx] = make_float4(x, y, z, SHIFTL + nb);
            (cloud ? wBaseGt : wBaseGen)[idx] = nb;
            (cloud ? g : f)[idx] = 0.0f;
            if (t == 0) out[0] = 0.0f;
        }
    }
    grid_barrier(blk);

    for (int it = 0; it < 20; ++it) {
        // f update: rows = gen, cols = gt (reads gtPack.w = h2(g))
        half_sweep(genPack, gtPack, wBaseGen, f, b, rowBase, tid);
        grid_barrier(blk);
        // g update: rows = gt, cols = gen (reads genPack.w = h2(f))
        half_sweep(gtPack, genPack, wBaseGt, g, b, rowBase, tid);
        grid_barrier(blk);
    }

    // ---- loss: += 0.5 * sum_ij exp((f_i+g_j-C_ij)/EPS) * C_ij
    {
        const float4* rp = genPack  + (size_t)b * N + rowBase;
        const float*  wb = wBaseGen + (size_t)b * N + rowBase;
        const float*  fp = f        + (size_t)b * N + rowBase;

        float Ax[RPB], Ay[RPB], Az[RPB], Ri[RPB], F2[RPB];
        #pragma unroll
        for (int r = 0; r < RPB; ++r) {
            float4 q = rp[r];
            Ax[r] = rfl(q.x * -2.0f);
            Ay[r] = rfl(q.y * -2.0f);
            Az[r] = rfl(q.z * -2.0f);
            Ri[r] = rfl(wb[r] * NLN2T);        // |p_i|^2
            F2[r] = rfl(fp[r] * C10L);
        }

        const float4* cp = gtPack + (size_t)b * N;
        const float*  gc = g      + (size_t)b * N;

        float acc = 0.0f;
        #pragma unroll
        for (int k = 0; k < KIT; ++k) {
            float4 p  = cp[tid + NT * k];
            float  gj = gc[tid + NT * k];
            float  G2 = gj * C10L;
            float  rj = fmaf(p.w - SHIFTL, NLN2T, gj);   // |p_j|^2
            #pragma unroll
            for (int r = 0; r < RPB; ++r) {
                float cc = rj + Ri[r];
                cc = fmaf(Az[r], p.z, cc);
                cc = fmaf(Ay[r], p.y, cc);
                cc = fmaf(Ax[r], p.x, cc);
                float arg = fmaf(cc, -C10L, G2 + F2[r]);
                acc = fmaf(fast_exp2(arg), cc, acc);
            }
        }

        acc += __shfl_xor(acc, 32);
        acc += __shfl_xor(acc, 16);
        acc += __shfl_xor(acc, 8);
        acc += __shfl_xor(acc, 4);
        acc += __shfl_xor(acc, 2);
        acc += __shfl_xor(acc, 1);
        __shared__ float sredL[NW];
        const int wave = tid >> 6, lane = tid & 63;
        if (lane == 0) sredL[wave] = acc;
        __syncthreads();
        if (tid == 0) {
            float t = 0.f;
            #pragma unroll
            for (int w = 0; w < NW; ++w) t += sredL[w];
            atomicAdd(out, t * 0.5f);
        }
    }
}

extern "C" void kernel_launch(void* const* d_in, const int* in_sizes, int n_in,
                              void* d_out, int out_size, void* d_ws, size_t ws_size,
                              hipStream_t stream) {
    const float* gen = (const float*)d_in[0];
    const float* gt  = (const float*)d_in[1];
    float* out = (float*)d_out;

    char* ws = (char*)d_ws;
    float4* genPack  = (float4*)ws;                        // 128 KB
    float4* gtPack   = (float4*)(ws + 128 * 1024);         // 128 KB
    float*  wBaseGen = (float*)(ws + 256 * 1024);          // 32 KB
    float*  wBaseGt  = (float*)(ws + 288 * 1024);          // 32 KB
    float*  f        = (float*)(ws + 320 * 1024);          // 16 KB
    float*  g        = f + 2 * N;                          // 16 KB

    fused_kernel<<<dim3(NBLK), dim3(NT), 0, stream>>>(
        gen, gt, genPack, gtPack, wBaseGen, wBaseGt, f, g, out);
}

// Round 10
// 686.776 us; speedup vs baseline: 2.1193x; 2.1193x over previous
//
#include <hip/hip_runtime.h>

// Entropic Sinkhorn EMD, B=2, N=4096, D=3, EPS=0.1, 20 iters.
// Round-10: single fused kernel (plain launch, co-residency by capacity:
// 512 blocks x 512 thr, <=128 VGPR -> 2 blocks/CU x 256 CU = 512 slots).
// R9's 35us/barrier was __threadfence() = full L2 writeback+inv per sweep
// (FETCH/WRITE ~22/24 MB of HBM churn). New design: NO fences at all.
// All cross-block mutable state (h2, f, g, barrier words) moves through the
// die-level Infinity Cache via relaxed SYSTEM-scope atomics (sc0 sc1 =
// bypass L1/L2); immutable packed points are written once via scoped stores
// in prep, then cached freely. Barrier = counter tree + 32 per-bucket epoch
// lines (16 spinners/line, s_sleep backoff), ordering by s_waitcnt vmcnt(0).

#define N    4096
#define NT   512
#define RPB  16     // rows per block
#define NBLK 512    // 256 blocks per batch x 2 batches
#define NW   (NT / 64)
#define KIT  (N / NT)

constexpr float EPS_F  = 0.1f;
constexpr float SHIFT  = 60.0f;
constexpr float LOG_A  = -8.317766166719343f;   // -log(4096)
constexpr float C10L   = 14.426950408889634f;   // 10*log2(e)
constexpr float C20L   = 28.853900817779268f;   // 20*log2(e)
constexpr float SHIFTL = 86.56170245333781f;    // SHIFT*log2(e)
constexpr float NLN2T  = -0.06931471805599453f; // -ln2/10
constexpr float LN2    = 0.6931471805599453f;

extern "C" __device__ float __ocml_native_exp2_f32(float);

__device__ __forceinline__ float fast_exp2(float x) {
#if __has_builtin(__builtin_amdgcn_exp2f)
    return __builtin_amdgcn_exp2f(x);
#else
    return __ocml_native_exp2_f32(x);
#endif
}

__device__ __forceinline__ float rfl(float x) {
    return __int_as_float(__builtin_amdgcn_readfirstlane(__float_as_int(x)));
}

// Relaxed system-scope ops: sc0 sc1 -> bypass L1/L2, served by Infinity Cache.
#define ALOADF(p)    __hip_atomic_load((p), __ATOMIC_RELAXED, __HIP_MEMORY_SCOPE_SYSTEM)
#define ASTOREF(p,v) __hip_atomic_store((p), (v), __ATOMIC_RELAXED, __HIP_MEMORY_SCOPE_SYSTEM)
#define AADDU(p,v)   __hip_atomic_fetch_add((p), (v), __ATOMIC_RELAXED, __HIP_MEMORY_SCOPE_SYSTEM)
#define VMWAIT()     asm volatile("s_waitcnt vmcnt(0)" ::: "memory")

// Barrier state: __device__ globals (zero at module load, monotone epoch ->
// consistent across graph replays; ws re-poison can't touch them).
struct alignas(128) PadU { unsigned int v; unsigned int pad[31]; };
__device__ PadU g_bucket[32];   // arrival counts (reset each round)
__device__ PadU g_root;         // bucket-completion count (reset each round)
__device__ PadU g_epoch;        // monotone master epoch
__device__ PadU g_bepoch[32];   // per-bucket published epoch (spin target)

struct GridBar {
    unsigned target;   // thread0-only: epoch value this block waits for next
    __device__ void init() {
        if (threadIdx.x == 0)
            target = __hip_atomic_load(&g_epoch.v, __ATOMIC_RELAXED,
                                       __HIP_MEMORY_SCOPE_SYSTEM);
        __syncthreads();
    }
    __device__ void sync(int blk) {
        VMWAIT();          // every wave: its scoped stores are LLC-visible
        __syncthreads();
        if (threadIdx.x == 0) {
            target += 1;
            const int bucket = blk & 31;
            unsigned old = AADDU(&g_bucket[bucket].v, 1u);
            if (old == (NBLK / 32) - 1) {
                ASTOREF(&g_bucket[bucket].v, 0u);
                VMWAIT();                       // reset lands before root add
                unsigned r = AADDU(&g_root.v, 1u);
                if (r == 31u) {
                    ASTOREF(&g_root.v, 0u);
                    AADDU(&g_epoch.v, 1u);      // monotone master
                    VMWAIT();                   // resets land before publish
                    #pragma unroll
                    for (int i = 0; i < 32; ++i) ASTOREF(&g_bepoch[i].v, target);
                }
            }
            while ((int)(__hip_atomic_load(&g_bepoch[bucket].v, __ATOMIC_RELAXED,
                                           __HIP_MEMORY_SCOPE_SYSTEM) - target) < 0)
                __builtin_amdgcn_s_sleep(4);
        }
        __syncthreads();
    }
};

// One half-sweep over this block's RPB rows. Row constants in SGPRs (from
// immutable cached pts); column h2 via 8 up-front scoped loads (LLC);
// column xyz via cached b128 loads. Epilogue scoped-stores dual + new h2.
__device__ __forceinline__ void half_sweep(
    const float4* ptsRow, const float4* ptsCol,
    const float* h2Col, float* h2RowOut, float* dualOut,
    int b, int rowBase, int tid)
{
    const float4* rp = ptsRow + (size_t)b * N + rowBase;

    float X[RPB], Y[RPB], Z[RPB], S[RPB];
    #pragma unroll
    for (int r = 0; r < RPB; ++r) {
        float4 q = rp[r];
        X[r] = rfl(q.x * C20L);
        Y[r] = rfl(q.y * C20L);
        Z[r] = rfl(q.z * C20L);
        S[r] = rfl(q.w);                   // -10L|p_i|^2
    }

    const float*  hc = h2Col + (size_t)b * N;
    const float4* cp = ptsCol + (size_t)b * N;

    float h2k[KIT];
    #pragma unroll
    for (int k = 0; k < KIT; ++k) h2k[k] = ALOADF(&hc[tid + NT * k]);

    float acc[RPB];
    #pragma unroll
    for (int r = 0; r < RPB; ++r) acc[r] = 0.0f;

    #pragma unroll
    for (int k = 0; k < KIT; ++k) {
        float4 p = cp[tid + NT * k];       // cached (immutable)
        float hv = h2k[k];                 // 10L*g_j + SHIFTL - 10L|p_j|^2
        #pragma unroll
        for (int r = 0; r < RPB; ++r) {
            float t = fmaf(Z[r], p.z, hv);
            t = fmaf(Y[r], p.y, t);
            t = fmaf(X[r], p.x, t);
            acc[r] += fast_exp2(t + S[r]);
        }
    }

    #pragma unroll
    for (int r = 0; r < RPB; ++r) {
        float a = acc[r];
        a += __shfl_xor(a, 32);
        a += __shfl_xor(a, 16);
        a += __shfl_xor(a, 8);
        a += __shfl_xor(a, 4);
        a += __shfl_xor(a, 2);
        a += __shfl_xor(a, 1);
        acc[r] = a;
    }
    __shared__ float sred[RPB][NW];
    const int wave = tid >> 6, lane = tid & 63;
    if (lane == 0) {
        #pragma unroll
        for (int r = 0; r < RPB; ++r) sred[r][wave] = acc[r];
    }
    __syncthreads();
    if (tid < RPB) {
        float s = 0.f;
        #pragma unroll
        for (int w = 0; w < NW; ++w) s += sred[tid][w];
        float dual = EPS_F * (LOG_A + SHIFT - log2f(s) * LN2);
        float nb = rp[tid].w;
        ASTOREF(&dualOut[(size_t)b * N + rowBase + tid], dual);
        ASTOREF(&h2RowOut[(size_t)b * N + rowBase + tid],
                fmaf(dual, C10L, SHIFTL + nb));
    }
    // grid_barrier follows (starts with VMWAIT + __syncthreads)
}

__global__ __launch_bounds__(NT, 4) void fused_kernel(
    const float* __restrict__ gen, const float* __restrict__ gt,
    float4* ptsGen, float4* ptsGt,
    float* h2Gen, float* h2Gt,
    float* f, float* g,
    float* out)
{
    const int tid = threadIdx.x;
    const int blk = blockIdx.x;        // 0..511
    const int b   = blk >> 8;          // 0 or 1
    const int rowBase = (blk & 255) * RPB;

    GridBar bar;
    bar.init();

    // ---- prep: pts {x,y,z,nb}, h2 = SHIFTL + nb (duals start at 0),
    //      f=g=0, out=0. All via scoped stores (cross-XCD first-read safe).
    {
        int t = blk * NT + tid;
        if (t < 16384) {
            int cloud = t >> 13;
            int idx   = t & 8191;      // b*N + j
            const float* src = cloud ? gt : gen;
            float x = src[idx * 3 + 0];
            float y = src[idx * 3 + 1];
            float z = src[idx * 3 + 2];
            float nb = -C10L * fmaf(z, z, fmaf(y, y, x * x));
            float* P = (float*)((cloud ? ptsGt : ptsGen) + idx);
            ASTOREF(&P[0], x);
            ASTOREF(&P[1], y);
            ASTOREF(&P[2], z);
            ASTOREF(&P[3], nb);
            ASTOREF(&(cloud ? h2Gt : h2Gen)[idx], SHIFTL + nb);
            ASTOREF(&(cloud ? g : f)[idx], 0.0f);
            if (t == 0) ASTOREF(out, 0.0f);
        }
    }
    bar.sync(blk);

    for (int it = 0; it < 20; ++it) {
        // f update: rows = gen, cols = gt (reads h2Gt), writes f + h2Gen
        half_sweep(ptsGen, ptsGt, h2Gt, h2Gen, f, b, rowBase, tid);
        bar.sync(blk);
        // g update: rows = gt, cols = gen (reads h2Gen), writes g + h2Gt
        half_sweep(ptsGt, ptsGen, h2Gen, h2Gt, g, b, rowBase, tid);
        bar.sync(blk);
    }

    // ---- loss: += 0.5 * sum_ij exp((f_i+g_j-C_ij)/EPS) * C_ij
    {
        const float4* rp = ptsGen + (size_t)b * N + rowBase;
        const float*  fp = f      + (size_t)b * N + rowBase;

        float Ax[RPB], Ay[RPB], Az[RPB], Ri[RPB], F2[RPB];
        #pragma unroll
        for (int r = 0; r < RPB; ++r) {
            float4 q = rp[r];
            Ax[r] = rfl(q.x * -2.0f);
            Ay[r] = rfl(q.y * -2.0f);
            Az[r] = rfl(q.z * -2.0f);
            Ri[r] = rfl(q.w * NLN2T);          // |p_i|^2
            F2[r] = rfl(ALOADF((float*)&fp[r]) * C10L);
        }

        const float4* cp = ptsGt + (size_t)b * N;
        const float*  gc = g     + (size_t)b * N;

        float gk[KIT];
        #pragma unroll
        for (int k = 0; k < KIT; ++k) gk[k] = ALOADF((float*)&gc[tid + NT * k]);

        float acc = 0.0f;
        #pragma unroll
        for (int k = 0; k < KIT; ++k) {
            float4 p  = cp[tid + NT * k];
            float  G2 = gk[k] * C10L;
            float  rj = p.w * NLN2T;           // |p_j|^2
            #pragma unroll
            for (int r = 0; r < RPB; ++r) {
                float cc = rj + Ri[r];
                cc = fmaf(Az[r], p.z, cc);
                cc = fmaf(Ay[r], p.y, cc);
                cc = fmaf(Ax[r], p.x, cc);
                float arg = fmaf(cc, -C10L, G2 + F2[r]);
                acc = fmaf(fast_exp2(arg), cc, acc);
            }
        }

        acc += __shfl_xor(acc, 32);
        acc += __shfl_xor(acc, 16);
        acc += __shfl_xor(acc, 8);
        acc += __shfl_xor(acc, 4);
        acc += __shfl_xor(acc, 2);
        acc += __shfl_xor(acc, 1);
        __shared__ float sredL[NW];
        const int wave = tid >> 6, lane = tid & 63;
        if (lane == 0) sredL[wave] = acc;
        __syncthreads();
        if (tid == 0) {
            float t = 0.f;
            #pragma unroll
            for (int w = 0; w < NW; ++w) t += sredL[w];
            __hip_atomic_fetch_add(out, t * 0.5f, __ATOMIC_RELAXED,
                                   __HIP_MEMORY_SCOPE_SYSTEM);
        }
    }
}

extern "C" void kernel_launch(void* const* d_in, const int* in_sizes, int n_in,
                              void* d_out, int out_size, void* d_ws, size_t ws_size,
                              hipStream_t stream) {
    const float* gen = (const float*)d_in[0];
    const float* gt  = (const float*)d_in[1];
    float* out = (float*)d_out;

    char* ws = (char*)d_ws;
    float4* ptsGen = (float4*)ws;                    // 128 KB [2][N]
    float4* ptsGt  = (float4*)(ws + 128 * 1024);     // 128 KB
    float*  h2Gen  = (float*)(ws + 256 * 1024);      // 32 KB
    float*  h2Gt   = (float*)(ws + 288 * 1024);      // 32 KB
    float*  f      = (float*)(ws + 320 * 1024);      // 32 KB
    float*  g      = (float*)(ws + 352 * 1024);      // 32 KB

    fused_kernel<<<dim3(NBLK), dim3(NT), 0, stream>>>(
        gen, gt, ptsGen, ptsGt, h2Gen, h2Gt, f, g, out);
}